// Round 1
// baseline (2176.309 us; speedup 1.0000x reference)
//
#include <hip/hip_runtime.h>
#include <math.h>

#define KDIM 200
#define CDIM 352
#define LDM  201          // row pitch: 200 matrix cols + 1 rhs col; bank stride 9 -> conflict-free
#define LMBDA 0.01f

// ---------------- Kernel 1: G = A A^T, R = B A^T (batched, tiled) ----------------
__global__ __launch_bounds__(256) void gemm_gr_kernel(
    const float* __restrict__ A, const float* __restrict__ B,
    float* __restrict__ G, float* __restrict__ R)
{
    __shared__ float As[32][33];
    __shared__ float Bs[32][33];
    const int tid = threadIdx.x;
    const int tx = tid & 15, ty = tid >> 4;
    const int z = blockIdx.z;
    const int b = z >> 1, which = z & 1;
    const float* Xb = (which ? B : A) + (size_t)b * KDIM * CDIM;
    const float* Ab = A + (size_t)b * KDIM * CDIM;
    float* O = (which ? R : G) + (size_t)b * KDIM * KDIM;
    const int tileM = blockIdx.y * 32;
    const int tileN = blockIdx.x * 32;

    const int lrow = tid >> 3;       // 0..31
    const int lc   = (tid & 7) * 4;  // 0..28

    float acc00 = 0.f, acc01 = 0.f, acc10 = 0.f, acc11 = 0.f;
    const int m0 = tileM + ty * 2, m1 = m0 + 1;
    const int n0 = tileN + tx * 2, n1 = n0 + 1;

    for (int kk = 0; kk < CDIM; kk += 32) {
        const int gm = tileM + lrow;
        const int gn = tileN + lrow;
        float4 va = make_float4(0.f, 0.f, 0.f, 0.f);
        float4 vb = make_float4(0.f, 0.f, 0.f, 0.f);
        if (gm < KDIM) va = *(const float4*)(Xb + (size_t)gm * CDIM + kk + lc);
        if (gn < KDIM) vb = *(const float4*)(Ab + (size_t)gn * CDIM + kk + lc);
        __syncthreads();   // protect previous iteration's reads
        As[lrow][lc + 0] = va.x; As[lrow][lc + 1] = va.y;
        As[lrow][lc + 2] = va.z; As[lrow][lc + 3] = va.w;
        Bs[lrow][lc + 0] = vb.x; Bs[lrow][lc + 1] = vb.y;
        Bs[lrow][lc + 2] = vb.z; Bs[lrow][lc + 3] = vb.w;
        __syncthreads();
        #pragma unroll
        for (int k = 0; k < 32; ++k) {
            float a0 = As[ty * 2][k], a1 = As[ty * 2 + 1][k];
            float b0 = Bs[tx * 2][k], b1 = Bs[tx * 2 + 1][k];
            acc00 = fmaf(a0, b0, acc00); acc01 = fmaf(a0, b1, acc01);
            acc10 = fmaf(a1, b0, acc10); acc11 = fmaf(a1, b1, acc11);
        }
    }
    if (m0 < KDIM) {
        if (n0 < KDIM) O[(size_t)m0 * KDIM + n0] = acc00;
        if (n1 < KDIM) O[(size_t)m0 * KDIM + n1] = acc01;
    }
    if (m1 < KDIM) {
        if (n0 < KDIM) O[(size_t)m1 * KDIM + n0] = acc10;
        if (n1 < KDIM) O[(size_t)m1 * KDIM + n1] = acc11;
    }
}

// ---------------- Kernel 2: per-(b,i) solve via LDS Gaussian elimination ----------------
__global__ __launch_bounds__(256) void solve_kernel(
    const float* __restrict__ G, const float* __restrict__ R,
    const float* __restrict__ ex, const float* __restrict__ ey,
    float* __restrict__ out)
{
    __shared__ float M[KDIM * LDM];   // 200*201*4 = 160,800 B
    __shared__ float red[8];

    const int sys = blockIdx.x;
    const int b = sys / KDIM;
    const int i = sys - b * KDIM;
    const int tid = threadIdx.x;

    // ---- per-batch scale = max(ex[b,:], ey[b,:]) ----
    float mx = 0.f;
    if (tid < KDIM) mx = fmaxf(ex[b * KDIM + tid], ey[b * KDIM + tid]);
    #pragma unroll
    for (int off = 32; off > 0; off >>= 1)
        mx = fmaxf(mx, __shfl_down(mx, off, 64));
    if ((tid & 63) == 0) red[tid >> 6] = mx;
    __syncthreads();
    if (tid == 0)
        red[0] = fmaxf(fmaxf(red[0], red[1]), fmaxf(red[2], red[3]));
    __syncthreads();
    const float scale = red[0];

    // ---- load G_b into LDS (float4 over rows; 200 % 4 == 0) ----
    const float* Gb = G + (size_t)b * KDIM * KDIM;
    for (int idx = tid; idx < KDIM * KDIM / 4; idx += 256) {
        const int r = idx / 50;           // 50 float4 per row
        const int c = (idx - r * 50) * 4;
        float4 v = ((const float4*)Gb)[idx];
        M[r * LDM + c + 0] = v.x;
        M[r * LDM + c + 1] = v.y;
        M[r * LDM + c + 2] = v.z;
        M[r * LDM + c + 3] = v.w;
    }
    // rhs column (column index 200): rhs_r = R[b, i, r]
    const float* Rrow = R + (size_t)b * KDIM * KDIM + (size_t)i * KDIM;
    for (int r = tid; r < KDIM; r += 256)
        M[r * LDM + KDIM] = Rrow[r];
    __syncthreads();

    // ---- add lambda * D[b,i,j] to diagonal ----
    // gamma = 0.5: e1_j^2 = ex_j/scale, e2_i^2 = ey_i/scale
    const float eyi = ey[b * KDIM + i] / scale;
    const float e2 = sqrtf(eyi);
    for (int j = tid; j < KDIM; j += 256) {
        const float exj = ex[b * KDIM + j] / scale;
        const float e1 = sqrtf(exj);
        const float denom = exj + eyi;
        const float re = e2 - e1;
        const float Dij = (re * re + 1.0f) / (denom * denom);
        M[j * LDM + j] += LMBDA * Dij;
    }

    // ---- forward elimination (no pivoting; SPD) ----
    for (int k = 0; k < KDIM - 1; ++k) {
        __syncthreads();
        const float invp = 1.0f / M[k * LDM + k];   // broadcast read
        const int r = k + 1 + tid;                  // one row per thread (<=199 rows)
        if (r < KDIM) {
            const float m = M[r * LDM + k] * invp;
            const float* __restrict__ prow = &M[k * LDM];
            float* __restrict__ rrow = &M[r * LDM];
            #pragma unroll 4
            for (int j = k + 1; j <= KDIM; ++j)     // includes rhs column (j == KDIM)
                rrow[j] = fmaf(-m, prow[j], rrow[j]);
        }
    }
    __syncthreads();

    // ---- back substitution: thread t owns row t, rhs in register ----
    float y = (tid < KDIM) ? M[tid * LDM + KDIM] : 0.f;
    for (int iRow = KDIM - 1; iRow >= 0; --iRow) {
        if (tid == iRow)
            M[iRow * LDM + KDIM] = y / M[iRow * LDM + iRow];
        __syncthreads();
        const float xi = M[iRow * LDM + KDIM];
        if (tid < iRow)
            y -= M[tid * LDM + iRow] * xi;
    }
    __syncthreads();

    // ---- store solution: Cxy[b, i, :] ----
    float* Orow = out + (size_t)b * KDIM * KDIM + (size_t)i * KDIM;
    for (int j = tid; j < KDIM; j += 256)
        Orow[j] = M[j * LDM + KDIM];
}

extern "C" void kernel_launch(void* const* d_in, const int* in_sizes, int n_in,
                              void* d_out, int out_size, void* d_ws, size_t ws_size,
                              hipStream_t stream) {
    const float* A  = (const float*)d_in[0];
    const float* B  = (const float*)d_in[1];
    const float* ex = (const float*)d_in[2];
    const float* ey = (const float*)d_in[3];
    float* out = (float*)d_out;

    float* G = (float*)d_ws;                   // 8*200*200 floats
    float* R = G + 8 * KDIM * KDIM;            // 8*200*200 floats

    dim3 grid1(7, 7, 16);                      // ceil(200/32) x ceil(200/32) x (8 batches * 2 outputs)
    gemm_gr_kernel<<<grid1, 256, 0, stream>>>(A, B, G, R);

    solve_kernel<<<1600, 256, 0, stream>>>(G, R, ex, ey, out);
}

// Round 2
// 1077.697 us; speedup vs baseline: 2.0194x; 2.0194x over previous
//
#include <hip/hip_runtime.h>
#include <math.h>

#define KDIM 200
#define CDIM 352
#define LDM  204          // 200 cols + rhs col (200) + pad(201..203); multiple of 4 for b128
#define NBP  20           // panel width; 200 = 10 * 20
#define NPAN 10
#define LMBDA 0.01f

__device__ __forceinline__ float4 ld4(const float* p) { return *(const float4*)p; }
__device__ __forceinline__ void st4(float* p, float4 v) { *(float4*)p = v; }

#define FMA4(c, a, u) \
    c.x = fmaf(-(a), u.x, c.x); c.y = fmaf(-(a), u.y, c.y); \
    c.z = fmaf(-(a), u.z, c.z); c.w = fmaf(-(a), u.w, c.w);

// ---------------- Kernel 1: G = A A^T, R = B A^T (batched, tiled) ----------------
__global__ __launch_bounds__(256) void gemm_gr_kernel(
    const float* __restrict__ A, const float* __restrict__ B,
    float* __restrict__ G, float* __restrict__ R)
{
    __shared__ float As[32][33];
    __shared__ float Bs[32][33];
    const int tid = threadIdx.x;
    const int tx = tid & 15, ty = tid >> 4;
    const int z = blockIdx.z;
    const int b = z >> 1, which = z & 1;
    const float* Xb = (which ? B : A) + (size_t)b * KDIM * CDIM;
    const float* Ab = A + (size_t)b * KDIM * CDIM;
    float* O = (which ? R : G) + (size_t)b * KDIM * KDIM;
    const int tileM = blockIdx.y * 32;
    const int tileN = blockIdx.x * 32;

    const int lrow = tid >> 3;
    const int lc   = (tid & 7) * 4;

    float acc00 = 0.f, acc01 = 0.f, acc10 = 0.f, acc11 = 0.f;
    const int m0 = tileM + ty * 2, m1 = m0 + 1;
    const int n0 = tileN + tx * 2, n1 = n0 + 1;

    for (int kk = 0; kk < CDIM; kk += 32) {
        const int gm = tileM + lrow;
        const int gn = tileN + lrow;
        float4 va = make_float4(0.f, 0.f, 0.f, 0.f);
        float4 vb = make_float4(0.f, 0.f, 0.f, 0.f);
        if (gm < KDIM) va = *(const float4*)(Xb + (size_t)gm * CDIM + kk + lc);
        if (gn < KDIM) vb = *(const float4*)(Ab + (size_t)gn * CDIM + kk + lc);
        __syncthreads();
        As[lrow][lc + 0] = va.x; As[lrow][lc + 1] = va.y;
        As[lrow][lc + 2] = va.z; As[lrow][lc + 3] = va.w;
        Bs[lrow][lc + 0] = vb.x; Bs[lrow][lc + 1] = vb.y;
        Bs[lrow][lc + 2] = vb.z; Bs[lrow][lc + 3] = vb.w;
        __syncthreads();
        #pragma unroll
        for (int k = 0; k < 32; ++k) {
            float a0 = As[ty * 2][k], a1 = As[ty * 2 + 1][k];
            float b0 = Bs[tx * 2][k], b1 = Bs[tx * 2 + 1][k];
            acc00 = fmaf(a0, b0, acc00); acc01 = fmaf(a0, b1, acc01);
            acc10 = fmaf(a1, b0, acc10); acc11 = fmaf(a1, b1, acc11);
        }
    }
    if (m0 < KDIM) {
        if (n0 < KDIM) O[(size_t)m0 * KDIM + n0] = acc00;
        if (n1 < KDIM) O[(size_t)m0 * KDIM + n1] = acc01;
    }
    if (m1 < KDIM) {
        if (n0 < KDIM) O[(size_t)m1 * KDIM + n0] = acc10;
        if (n1 < KDIM) O[(size_t)m1 * KDIM + n1] = acc11;
    }
}

// ---------------- Kernel 2: per-(b,i) blocked LU solve in LDS ----------------
__global__ __launch_bounds__(256) void solve_kernel(
    const float* __restrict__ G, const float* __restrict__ R,
    const float* __restrict__ ex, const float* __restrict__ ey,
    float* __restrict__ out)
{
    __shared__ float M[KDIM * LDM];   // 200*204*4 = 163,200 B
    __shared__ float red[4];

    const int sys = blockIdx.x;
    const int b = sys / KDIM;
    const int i = sys - b * KDIM;
    const int tid = threadIdx.x;
    const int bK = b * KDIM;

    // ---- per-batch scale = max(ex[b,:], ey[b,:]) ----
    float mx = 0.f;
    if (tid < KDIM) mx = fmaxf(ex[bK + tid], ey[bK + tid]);
    #pragma unroll
    for (int off = 32; off > 0; off >>= 1)
        mx = fmaxf(mx, __shfl_down(mx, off, 64));
    if ((tid & 63) == 0) red[tid >> 6] = mx;

    // ---- load G_b (row-major float4) + rhs col + zero pads ----
    const float* Gb = G + (size_t)b * KDIM * KDIM;
    for (int idx = tid; idx < KDIM * KDIM / 4; idx += 256) {
        const int r = idx / 50;                 // 50 float4 per source row
        const int c = (idx - r * 50) * 4;       // idx*4 == r*200 + c
        st4(&M[r * LDM + c], ld4(Gb + (size_t)idx * 4));
    }
    const float* Rrow = R + (size_t)b * KDIM * KDIM + (size_t)i * KDIM;
    for (int r = tid; r < KDIM; r += 256) {
        M[r * LDM + 200] = Rrow[r];
        M[r * LDM + 201] = 0.f;
        M[r * LDM + 202] = 0.f;
        M[r * LDM + 203] = 0.f;
    }
    __syncthreads();

    // ---- diagonal regularizer: + lambda * D[b,i,j] ----
    const float scale = fmaxf(fmaxf(red[0], red[1]), fmaxf(red[2], red[3]));
    const float eyi = ey[bK + i] / scale;
    const float e2 = sqrtf(eyi);
    for (int j = tid; j < KDIM; j += 256) {
        const float exj = ex[bK + j] / scale;
        const float e1 = sqrtf(exj);
        const float denom = exj + eyi;
        const float re = e2 - e1;
        M[j * LDM + j] += LMBDA * ((re * re + 1.0f) / (denom * denom));
    }

    // ---- blocked LU, no pivoting (SPD + positive diagonal shift) ----
    for (int p = 0; p < NPAN; ++p) {
        const int p0 = p * NBP, p1 = p0 + NBP;

        // panel factorization: per-column elimination on panel cols only
        for (int c = p0; c < p1; ++c) {
            __syncthreads();
            const float invp = 1.0f / M[c * LDM + c];
            const int r = c + 1 + tid;
            if (r < KDIM) {
                float* __restrict__ row = &M[r * LDM];
                const float* __restrict__ prow = &M[c * LDM];
                const float m = row[c] * invp;
                row[c] = m;
                for (int j = c + 1; j < p1; ++j)
                    row[j] = fmaf(-m, prow[j], row[j]);
            }
        }
        __syncthreads();

        // U12 strip: rows p0..p1-1, cols p1..203 — one thread per column, no barriers
        {
            const int j = p1 + tid;
            if (j < LDM) {
                float u[NBP];
                #pragma unroll
                for (int t = 0; t < NBP; ++t) {
                    float a = M[(p0 + t) * LDM + j];
                    #pragma unroll
                    for (int s = 0; s < t; ++s)
                        a = fmaf(-M[(p0 + t) * LDM + p0 + s], u[s], a);
                    u[t] = a;
                    M[(p0 + t) * LDM + j] = a;
                }
            }
        }
        __syncthreads();

        // trailing update: C -= L(panel cols) * U(strip), rank-20, 4x4 float4 tiles
        if (p1 < KDIM) {
            const int ty4 = (tid >> 5) * 4;     // row-block offset 0..28
            const int txc = tid & 31;           // chunk lane
            for (int rb = p1 + ty4; rb < KDIM; rb += 32) {
                float* row0 = &M[rb * LDM];
                float* row1 = row0 + LDM;
                float* row2 = row1 + LDM;
                float* row3 = row2 + LDM;
                for (int cc = (p1 >> 2) + txc; cc <= 50; cc += 32) {
                    const int co = cc * 4;
                    float4 c0 = ld4(row0 + co), c1 = ld4(row1 + co);
                    float4 c2 = ld4(row2 + co), c3 = ld4(row3 + co);
                    #pragma unroll
                    for (int t0 = 0; t0 < NBP; t0 += 4) {
                        float4 l0 = ld4(row0 + p0 + t0);
                        float4 l1 = ld4(row1 + p0 + t0);
                        float4 l2 = ld4(row2 + p0 + t0);
                        float4 l3 = ld4(row3 + p0 + t0);
                        float4 u0 = ld4(&M[(p0 + t0    ) * LDM + co]);
                        float4 u1 = ld4(&M[(p0 + t0 + 1) * LDM + co]);
                        float4 u2 = ld4(&M[(p0 + t0 + 2) * LDM + co]);
                        float4 u3 = ld4(&M[(p0 + t0 + 3) * LDM + co]);
                        FMA4(c0, l0.x, u0); FMA4(c0, l0.y, u1); FMA4(c0, l0.z, u2); FMA4(c0, l0.w, u3);
                        FMA4(c1, l1.x, u0); FMA4(c1, l1.y, u1); FMA4(c1, l1.z, u2); FMA4(c1, l1.w, u3);
                        FMA4(c2, l2.x, u0); FMA4(c2, l2.y, u1); FMA4(c2, l2.z, u2); FMA4(c2, l2.w, u3);
                        FMA4(c3, l3.x, u0); FMA4(c3, l3.y, u1); FMA4(c3, l3.z, u2); FMA4(c3, l3.w, u3);
                    }
                    st4(row0 + co, c0); st4(row1 + co, c1);
                    st4(row2 + co, c2); st4(row3 + co, c3);
                }
            }
        }
        // next panel's column loop begins with __syncthreads()
    }

    // ---- blocked back-substitution ----
    for (int p = NPAN - 1; p >= 0; --p) {
        const int p0 = p * NBP;
        __syncthreads();
        // 20x20 upper-tri solve by wave 0 via shfl (no barriers)
        if (tid < 64) {
            float rhs = 0.f;
            if (tid < NBP) rhs = M[(p0 + tid) * LDM + 200];
            #pragma unroll
            for (int t = NBP - 1; t >= 0; --t) {
                const float diag = M[(p0 + t) * LDM + p0 + t];
                const float x_t = __shfl(rhs, t, 64) / diag;
                if (tid < t) rhs = fmaf(-M[(p0 + tid) * LDM + p0 + t], x_t, rhs);
                if (tid == t) M[(p0 + t) * LDM + 200] = x_t;
            }
        }
        __syncthreads();
        // rank-20 rhs update for rows above (one row per thread; p0 <= 180 < 256)
        if (tid < p0) {
            const int r = tid;
            float acc = M[r * LDM + 200];
            #pragma unroll
            for (int t0 = 0; t0 < NBP; t0 += 4) {
                float4 lv = ld4(&M[r * LDM + p0 + t0]);
                acc = fmaf(-lv.x, M[(p0 + t0    ) * LDM + 200], acc);
                acc = fmaf(-lv.y, M[(p0 + t0 + 1) * LDM + 200], acc);
                acc = fmaf(-lv.z, M[(p0 + t0 + 2) * LDM + 200], acc);
                acc = fmaf(-lv.w, M[(p0 + t0 + 3) * LDM + 200], acc);
            }
            M[r * LDM + 200] = acc;
        }
    }
    __syncthreads();

    // ---- store Cxy[b, i, :] ----
    float* Orow = out + (size_t)b * KDIM * KDIM + (size_t)i * KDIM;
    for (int jj = tid; jj < KDIM; jj += 256)
        Orow[jj] = M[jj * LDM + 200];
}

extern "C" void kernel_launch(void* const* d_in, const int* in_sizes, int n_in,
                              void* d_out, int out_size, void* d_ws, size_t ws_size,
                              hipStream_t stream) {
    const float* A  = (const float*)d_in[0];
    const float* B  = (const float*)d_in[1];
    const float* ex = (const float*)d_in[2];
    const float* ey = (const float*)d_in[3];
    float* out = (float*)d_out;

    float* G = (float*)d_ws;
    float* R = G + 8 * KDIM * KDIM;

    dim3 grid1(7, 7, 16);
    gemm_gr_kernel<<<grid1, 256, 0, stream>>>(A, B, G, R);

    solve_kernel<<<1600, 256, 0, stream>>>(G, R, ex, ey, out);
}

// Round 3
// 915.892 us; speedup vs baseline: 2.3762x; 1.1767x over previous
//
#include <hip/hip_runtime.h>
#include <math.h>

#define KD 200
#define CD 352
#define NBP 20
#define NPAN 10
#define LMB 0.01f

__device__ __forceinline__ float4 ld4(const float* p) { return *(const float4*)p; }
__device__ __forceinline__ void st4(float* p, float4 v) { *(float4*)p = v; }

#define COMP(v,k) ((k)==0?(v).x:((k)==1?(v).y:((k)==2?(v).z:(v).w)))
#define FMA4(c,a,u) { c.x=fmaf(-(a),(u).x,c.x); c.y=fmaf(-(a),(u).y,c.y); \
                      c.z=fmaf(-(a),(u).z,c.z); c.w=fmaf(-(a),(u).w,c.w); }

// ---------------- Kernel 1: G = A A^T, R = B A^T (batched, tiled) ----------------
__global__ __launch_bounds__(256) void gemm_gr_kernel(
    const float* __restrict__ A, const float* __restrict__ B,
    float* __restrict__ G, float* __restrict__ R)
{
    __shared__ float As[32][33];
    __shared__ float Bs[32][33];
    const int tid = threadIdx.x;
    const int tx = tid & 15, ty = tid >> 4;
    const int z = blockIdx.z;
    const int b = z >> 1, which = z & 1;
    const float* Xb = (which ? B : A) + (size_t)b * KD * CD;
    const float* Ab = A + (size_t)b * KD * CD;
    float* O = (which ? R : G) + (size_t)b * KD * KD;
    const int tileM = blockIdx.y * 32;
    const int tileN = blockIdx.x * 32;

    const int lrow = tid >> 3;
    const int lc   = (tid & 7) * 4;

    float acc00 = 0.f, acc01 = 0.f, acc10 = 0.f, acc11 = 0.f;
    const int m0 = tileM + ty * 2, m1 = m0 + 1;
    const int n0 = tileN + tx * 2, n1 = n0 + 1;

    for (int kk = 0; kk < CD; kk += 32) {
        const int gm = tileM + lrow;
        const int gn = tileN + lrow;
        float4 va = make_float4(0.f, 0.f, 0.f, 0.f);
        float4 vb = make_float4(0.f, 0.f, 0.f, 0.f);
        if (gm < KD) va = *(const float4*)(Xb + (size_t)gm * CD + kk + lc);
        if (gn < KD) vb = *(const float4*)(Ab + (size_t)gn * CD + kk + lc);
        __syncthreads();
        As[lrow][lc + 0] = va.x; As[lrow][lc + 1] = va.y;
        As[lrow][lc + 2] = va.z; As[lrow][lc + 3] = va.w;
        Bs[lrow][lc + 0] = vb.x; Bs[lrow][lc + 1] = vb.y;
        Bs[lrow][lc + 2] = vb.z; Bs[lrow][lc + 3] = vb.w;
        __syncthreads();
        #pragma unroll
        for (int k = 0; k < 32; ++k) {
            float a0 = As[ty * 2][k], a1 = As[ty * 2 + 1][k];
            float b0 = Bs[tx * 2][k], b1 = Bs[tx * 2 + 1][k];
            acc00 = fmaf(a0, b0, acc00); acc01 = fmaf(a0, b1, acc01);
            acc10 = fmaf(a1, b0, acc10); acc11 = fmaf(a1, b1, acc11);
        }
    }
    if (m0 < KD) {
        if (n0 < KD) O[(size_t)m0 * KD + n0] = acc00;
        if (n1 < KD) O[(size_t)m0 * KD + n1] = acc01;
    }
    if (m1 < KD) {
        if (n0 < KD) O[(size_t)m1 * KD + n0] = acc10;
        if (n1 < KD) O[(size_t)m1 * KD + n1] = acc11;
    }
}

// ---------------- Kernel 2: per-(b,i) blocked LU solve, column-major LDS ----------------
// M is COLUMN-major: element (row r, col c) at M[c*KD + r]. G symmetric -> plain copy.
// Column accesses (lanes over rows) are contiguous -> conflict-free.
__global__ __launch_bounds__(512, 2) void solve_kernel(
    const float* __restrict__ G, const float* __restrict__ R,
    const float* __restrict__ ex, const float* __restrict__ ey,
    float* __restrict__ out)
{
    __shared__ __align__(16) float M[KD * KD];      // 160,000 B
    __shared__ __align__(16) float rhs[KD + 8];
    __shared__ __align__(16) float buf[2][32];      // published pivot row (double-buffered)
    __shared__ float red[8];

    const int tid = threadIdx.x;
    const int sys = blockIdx.x;
    const int b = sys / KD;
    const int i = sys - b * KD;
    const int bK = b * KD;

    // ---- per-batch scale = max(ex, ey) ----
    float mx = 0.f;
    if (tid < KD) mx = fmaxf(ex[bK + tid], ey[bK + tid]);
    #pragma unroll
    for (int off = 32; off > 0; off >>= 1)
        mx = fmaxf(mx, __shfl_down(mx, off, 64));
    if ((tid & 63) == 0) red[tid >> 6] = mx;

    // ---- load G (symmetric: col-major == row-major copy) ----
    const float* Gb = G + (size_t)b * KD * KD;
    for (int idx = tid; idx < KD * KD / 4; idx += 512)
        st4(&M[idx * 4], ld4(Gb + (size_t)idx * 4));

    // rhs held in a register per owning thread for the whole factorization
    float rhs_reg = 0.f;
    const float* Rrow = R + (size_t)b * KD * KD + (size_t)i * KD;
    if (tid < KD) rhs_reg = Rrow[tid];
    __syncthreads();

    if (tid == 0) {
        float s = red[0];
        #pragma unroll
        for (int w = 1; w < 8; ++w) s = fmaxf(s, red[w]);
        red[0] = s;
    }
    __syncthreads();

    // ---- diagonal regularizer ----
    const float scale = red[0];
    const float eyi = ey[bK + i] / scale;
    const float e2 = sqrtf(eyi);
    if (tid < KD) {
        const float exj = ex[bK + tid] / scale;
        const float e1 = sqrtf(exj);
        const float dn = exj + eyi;
        const float re = e2 - e1;
        M[tid * KD + tid] += LMB * ((re * re + 1.f) / (dn * dn));
    }

    // ---- blocked LU (no pivoting; SPD) ----
    for (int p = 0; p < NPAN; ++p) {
        const int p0 = p * NBP, p1 = p0 + NBP;
        __syncthreads();

        // thread r = tid keeps its panel row slice in registers
        float pr[NBP];
        if (tid < KD && tid >= p0) {
            #pragma unroll
            for (int j = 0; j < NBP; ++j)
                pr[j] = M[(p0 + j) * KD + tid];
        }

        #pragma unroll
        for (int c = 0; c < NBP; ++c) {
            const int ca = p0 + c;
            const int par = c & 1;
            // pivot publishes its (fully updated) row + rhs
            if (tid == ca) {
                #pragma unroll
                for (int q = 0; q < 5; ++q)
                    st4(&buf[par][4 * q],
                        make_float4(pr[4*q], pr[4*q+1], pr[4*q+2], pr[4*q+3]));
                buf[par][20] = rhs_reg;
            }
            __syncthreads();
            if (tid < KD && tid > ca) {
                const float m = pr[c] * (1.0f / buf[par][c]);
                rhs_reg = fmaf(-m, buf[par][20], rhs_reg);
                M[ca * KD + tid] = m;                 // L column, contiguous lanes
                #pragma unroll
                for (int q = c >> 2; q < 5; ++q) {    // lower quarters are all-zero: skip
                    const float4 bq = ld4(&buf[par][4 * q]);
                    pr[4*q+0] = fmaf(-m, bq.x, pr[4*q+0]);
                    pr[4*q+1] = fmaf(-m, bq.y, pr[4*q+1]);
                    pr[4*q+2] = fmaf(-m, bq.z, pr[4*q+2]);
                    pr[4*q+3] = fmaf(-m, bq.w, pr[4*q+3]);
                }
            }
            // wave 7 persists the published U row into M's diagonal block
            const int j7 = tid - 448;
            if (j7 >= c && j7 < NBP)
                M[(p0 + j7) * KD + ca] = buf[par][j7];
        }
        __syncthreads();

        // ---- U12 strip: L11^{-1} * A12, one thread per column, register recursion ----
        {
            const int j = p1 + tid;
            if (j < KD) {
                float u[NBP];
                #pragma unroll
                for (int q = 0; q < 5; ++q) {
                    const float4 a4 = ld4(&M[j * KD + p0 + 4 * q]);
                    u[4*q+0] = a4.x; u[4*q+1] = a4.y; u[4*q+2] = a4.z; u[4*q+3] = a4.w;
                }
                #pragma unroll
                for (int s = 0; s < NBP - 1; ++s) {
                    #pragma unroll
                    for (int q = (s + 1) >> 2; q < 5; ++q) {
                        const float4 l4 = ld4(&M[(p0 + s) * KD + p0 + 4 * q]); // broadcast
                        if (4*q+0 > s) u[4*q+0] = fmaf(-l4.x, u[s], u[4*q+0]);
                        if (4*q+1 > s) u[4*q+1] = fmaf(-l4.y, u[s], u[4*q+1]);
                        if (4*q+2 > s) u[4*q+2] = fmaf(-l4.z, u[s], u[4*q+2]);
                        if (4*q+3 > s) u[4*q+3] = fmaf(-l4.w, u[s], u[4*q+3]);
                    }
                }
                #pragma unroll
                for (int q = 0; q < 5; ++q)
                    st4(&M[j * KD + p0 + 4 * q],
                        make_float4(u[4*q], u[4*q+1], u[4*q+2], u[4*q+3]));
            }
        }
        __syncthreads();

        // ---- trailing update: C(r>p1, j>p1) -= L(:,p0..p1) * U(p0..p1, :) ----
        if (p1 < KD) {
            const int cg = tid >> 5;        // 16 column groups of 4 columns
            const int lane = tid & 31;      // contiguous row chunks
            for (int jb0 = p1; jb0 < KD; jb0 += 64) {
                const int jb = jb0 + cg * 4;
                if (jb < KD) {
                    float4 uT[4][5];        // U values for this column block (registers)
                    #pragma unroll
                    for (int jj = 0; jj < 4; ++jj)
                        #pragma unroll
                        for (int q = 0; q < 5; ++q)
                            uT[jj][q] = ld4(&M[(jb + jj) * KD + p0 + 4 * q]);
                    for (int ro = p1 + lane * 4; ro < KD; ro += 128) {
                        float4 c0 = ld4(&M[(jb + 0) * KD + ro]);
                        float4 c1 = ld4(&M[(jb + 1) * KD + ro]);
                        float4 c2 = ld4(&M[(jb + 2) * KD + ro]);
                        float4 c3 = ld4(&M[(jb + 3) * KD + ro]);
                        #pragma unroll
                        for (int t = 0; t < NBP; ++t) {
                            const float4 lv = ld4(&M[(p0 + t) * KD + ro]);
                            FMA4(c0, COMP(uT[0][t >> 2], t & 3), lv);
                            FMA4(c1, COMP(uT[1][t >> 2], t & 3), lv);
                            FMA4(c2, COMP(uT[2][t >> 2], t & 3), lv);
                            FMA4(c3, COMP(uT[3][t >> 2], t & 3), lv);
                        }
                        st4(&M[(jb + 0) * KD + ro], c0);
                        st4(&M[(jb + 1) * KD + ro], c1);
                        st4(&M[(jb + 2) * KD + ro], c2);
                        st4(&M[(jb + 3) * KD + ro], c3);
                    }
                }
            }
        }
    }

    // ---- back-substitution (blocked) ----
    __syncthreads();
    if (tid < KD) rhs[tid] = rhs_reg;
    __syncthreads();
    for (int p = NPAN - 1; p >= 0; --p) {
        const int p0 = p * NBP;
        if (tid < 64) {
            float rv = (tid < NBP) ? rhs[p0 + tid] : 0.f;
            #pragma unroll
            for (int t = NBP - 1; t >= 0; --t) {
                const float xt = __shfl(rv, t, 64) / M[(p0 + t) * KD + p0 + t];
                if (tid < t) rv = fmaf(-M[(p0 + t) * KD + p0 + tid], xt, rv);
                if (tid == t) rhs[p0 + t] = xt;
            }
        }
        __syncthreads();
        if (tid < p0) {
            float acc = rhs[tid];
            #pragma unroll
            for (int q = 0; q < 5; ++q) {
                const float4 x4 = ld4(&rhs[p0 + 4 * q]);          // broadcast
                acc = fmaf(-M[(p0 + 4*q + 0) * KD + tid], x4.x, acc);
                acc = fmaf(-M[(p0 + 4*q + 1) * KD + tid], x4.y, acc);
                acc = fmaf(-M[(p0 + 4*q + 2) * KD + tid], x4.z, acc);
                acc = fmaf(-M[(p0 + 4*q + 3) * KD + tid], x4.w, acc);
            }
            rhs[tid] = acc;
        }
        __syncthreads();
    }

    // ---- store Cxy[b, i, :] ----
    float* Orow = out + (size_t)b * KD * KD + (size_t)i * KD;
    if (tid < KD / 4)
        *(float4*)&Orow[tid * 4] = ld4(&rhs[tid * 4]);
}

extern "C" void kernel_launch(void* const* d_in, const int* in_sizes, int n_in,
                              void* d_out, int out_size, void* d_ws, size_t ws_size,
                              hipStream_t stream) {
    const float* A  = (const float*)d_in[0];
    const float* B  = (const float*)d_in[1];
    const float* ex = (const float*)d_in[2];
    const float* ey = (const float*)d_in[3];
    float* out = (float*)d_out;

    float* G = (float*)d_ws;
    float* R = G + 8 * KD * KD;

    dim3 grid1(7, 7, 16);
    gemm_gr_kernel<<<grid1, 256, 0, stream>>>(A, B, G, R);

    solve_kernel<<<1600, 512, 0, stream>>>(G, R, ex, ey, out);
}